// Round 11
// baseline (87.602 us; speedup 1.0000x reference)
//
#include <hip/hip_runtime.h>
#include <math.h>

// Problem constants
#define F_ 126
#define NPG 128              // nodes per graph
#define EPG 2048             // edges per graph
#define ET 524288            // total edges
#define NEG_SLOPE 0.2f

typedef short bf16x8 __attribute__((ext_vector_type(8)));
typedef float f32x4 __attribute__((ext_vector_type(4)));

__device__ __forceinline__ float bf2f(unsigned short u) {
  return __uint_as_float(((unsigned)u) << 16);
}
__device__ __forceinline__ unsigned short f2bf(float f) {
  unsigned x = __float_as_uint(f);
  unsigned r = x + 0x7fffu + ((x >> 16) & 1u);   // RNE
  return (unsigned short)(r >> 16);
}
// single-instruction packed f32x2 -> bf16x2 (RNE), gfx950
__device__ __forceinline__ unsigned cvtpk(float lo, float hi) {
  unsigned r;
  asm("v_cvt_pk_bf16_f32 %0, %1, %2" : "=v"(r) : "v"(lo), "v"(hi));
  return r;
}
union bfpack { unsigned u[4]; bf16x8 v; };

#define SW(r)  (((r) & 7) << 4)    // bf16-row swizzle (16B granule)
#define SWB(d) (((d) & 15) << 3)   // byte-matrix swizzle (8B granule)

// ws layout (bytes):
//   [0, 393216)                wct bf16 [3][256][256]
//   [393216, +4MB)             M u8 [256 g][16384]  (SWB-swizzled)
//   [4587520, +2MB)            tab f32 [256 g][4 tbl][4 hd][128]  (Es,Fs,Ed,Fd)
//   [6684672, +16MB)           hT bf16 [256 g][256 dim][128 src]
#define WS_M    393216
#define WS_TAB  4587520
#define WS_HT   6684672

// ---------------- K0P: wct (coalesced) + M multiplicity build + out zero ------------------
__global__ __launch_bounds__(256) void k0p(
    const float* __restrict__ Wf, const float* __restrict__ Wu,
    const float* __restrict__ Wi, const float* __restrict__ Wg,
    const int* __restrict__ ei,
    unsigned short* __restrict__ wct, unsigned char* __restrict__ Mws,
    float* __restrict__ out) {
  const int blk = blockIdx.x;
  const int tid = threadIdx.x;
  if (blk < 96) {
    // WcT[type][c][k] = sum_j Wx[k][j] * Wg[j][c]; block = (type, 8-k-row chunk)
    const int type = blk / 32;
    const int kc = blk % 32;
    const float* Wx = (type == 0) ? Wf : ((type == 1) ? Wu : Wi);
    __shared__ float Xs[8][256];
#pragma unroll
    for (int r = 0; r < 8; ++r) Xs[r][tid] = Wx[(kc * 8 + r) * 256 + tid];  // coalesced
    __syncthreads();
    float acc[8] = {};
#pragma unroll 16
    for (int j = 0; j < 256; ++j) {
      float wg = Wg[j * 256 + tid];                // coalesced across threads
#pragma unroll
      for (int r = 0; r < 8; ++r) acc[r] += Xs[r][j] * wg;
    }
#pragma unroll
    for (int r = 0; r < 8; ++r)
      wct[((size_t)type * 256 + tid) * 256 + kc * 8 + r] = f2bf(acc[r]);
  } else {
    // per-graph M build (byte-packed multiplicity, SWB-swizzled) + out zero
    const int g = blk - 96;
    if (tid < F_) out[(size_t)g * F_ + tid] = 0.f;
    __shared__ __align__(16) unsigned char Ml[16384];
    {
      uint4 z = { 0, 0, 0, 0 };
#pragma unroll
      for (int i = 0; i < 4; ++i) *(uint4*)(Ml + tid * 16 + i * 4096) = z;
    }
    int4 sa = *(const int4*)(ei + (size_t)g * EPG + tid * 8);
    int4 sb = *(const int4*)(ei + (size_t)g * EPG + tid * 8 + 4);
    int4 da = *(const int4*)(ei + (size_t)ET + (size_t)g * EPG + tid * 8);
    int4 db = *(const int4*)(ei + (size_t)ET + (size_t)g * EPG + tid * 8 + 4);
    __syncthreads();
    int ss[8] = { sa.x - g * NPG, sa.y - g * NPG, sa.z - g * NPG, sa.w - g * NPG,
                  sb.x - g * NPG, sb.y - g * NPG, sb.z - g * NPG, sb.w - g * NPG };
    int dd[8] = { da.x - g * NPG, da.y - g * NPG, da.z - g * NPG, da.w - g * NPG,
                  db.x - g * NPG, db.y - g * NPG, db.z - g * NPG, db.w - g * NPG };
#pragma unroll
    for (int j = 0; j < 8; ++j) {
      int bofs = (dd[j] * 128 + ss[j]) ^ SWB(dd[j]);
      atomicAdd((int*)(Ml + (bofs & ~3)), 1 << ((bofs & 3) * 8));
    }
    __syncthreads();
    unsigned char* Mdst = Mws + (size_t)g * 16384;
#pragma unroll
    for (int i = 0; i < 4; ++i)
      *(uint4*)(Mdst + tid * 16 + i * 4096) = *(const uint4*)(Ml + tid * 16 + i * 4096);
  }
}

// ---------------- K1: GEMM1 (gather) + GEMV + exp tables + hT ----------------------------
// 512 blocks = (g, rh row-half); 512 threads, 8 waves: wave = 16 rows x 128 dims.
__global__ __launch_bounds__(512, 4) void k1(
    const int* __restrict__ fid, const int* __restrict__ userid, const int* __restrict__ itemid,
    const float* __restrict__ ftab, const float* __restrict__ utab, const float* __restrict__ itab,
    const unsigned short* __restrict__ wct,
    const float* __restrict__ a_src, const float* __restrict__ a_dst,
    float* __restrict__ tabws, unsigned short* __restrict__ hTws) {
  const int g = blockIdx.x & 255;
  const int rh = blockIdx.x >> 8;
  const int tid = threadIdx.x;
  const int lane = tid & 63;
  const int wid = tid >> 6;            // 0..7
  const int rl = lane & 15;
  const int kg = lane >> 4;

  __shared__ float asl[256], adl[256];
  if (tid < 256) asl[tid] = a_src[tid];
  else           adl[tid - 256] = a_dst[tid - 256];
  __syncthreads();

  const int rowg = wid & 3, dimh = wid >> 2;
  const int row0 = rh * 64 + rowg * 16;
  const int arow = row0 + rl;
  const float* rp;
  if (arow < F_)       rp = ftab + (size_t)fid[g * F_ + arow] * 256;
  else if (arow == F_) rp = utab + (size_t)userid[g] * 256;   // placeholder; GEMV overwrites
  else                 rp = itab + (size_t)itemid[g] * 256;
  const unsigned short* bp[8];
#pragma unroll
  for (int nf = 0; nf < 8; ++nf)
    bp[nf] = wct + (size_t)(dimh * 128 + nf * 16 + rl) * 256;

  f32x4 acc[8] = {};
#pragma unroll
  for (int ks = 0; ks < 8; ++ks) {
    float4 v0 = *(const float4*)(rp + ks * 32 + kg * 8);
    float4 v1 = *(const float4*)(rp + ks * 32 + kg * 8 + 4);
    bfpack p;
    p.u[0] = cvtpk(v0.x, v0.y); p.u[1] = cvtpk(v0.z, v0.w);
    p.u[2] = cvtpk(v1.x, v1.y); p.u[3] = cvtpk(v1.z, v1.w);
#pragma unroll
    for (int nf = 0; nf < 8; ++nf) {
      bf16x8 bfv = *(const bf16x8*)(bp[nf] + ks * 32 + kg * 8);
      acc[nf] = __builtin_amdgcn_mfma_f32_16x16x32_bf16(p.v, bfv, acc[nf], 0, 0, 0);
    }
  }

  // exp tables from f32 acc (heads dimh*2, dimh*2+1)
  {
    float asv[8], adv[8];
#pragma unroll
    for (int nf = 0; nf < 8; ++nf) {
      asv[nf] = asl[dimh * 128 + nf * 16 + rl];
      adv[nf] = adl[dimh * 128 + nf * 16 + rl];
    }
    float* tb = tabws + (size_t)g * 2048;
#pragma unroll
    for (int i = 0; i < 4; ++i) {
      float ps0 = 0.f, ps1 = 0.f, pd0 = 0.f, pd1 = 0.f;
#pragma unroll
      for (int nf = 0; nf < 4; ++nf) {
        ps0 += acc[nf][i] * asv[nf];     pd0 += acc[nf][i] * adv[nf];
        ps1 += acc[nf + 4][i] * asv[nf + 4]; pd1 += acc[nf + 4][i] * adv[nf + 4];
      }
#pragma unroll
      for (int d2 = 1; d2 < 16; d2 <<= 1) {
        ps0 += __shfl_xor(ps0, d2); ps1 += __shfl_xor(ps1, d2);
        pd0 += __shfl_xor(pd0, d2); pd1 += __shfl_xor(pd1, d2);
      }
      int row = row0 + kg * 4 + i;
      if (rl == 0 && row < F_) {
        int h0 = dimh * 2, h1 = h0 + 1;
        tb[0 * 512 + h0 * 128 + row] = __expf(ps0);
        tb[1 * 512 + h0 * 128 + row] = __expf(NEG_SLOPE * ps0);
        tb[2 * 512 + h0 * 128 + row] = __expf(pd0);
        tb[3 * 512 + h0 * 128 + row] = __expf(NEG_SLOPE * pd0);
        tb[0 * 512 + h1 * 128 + row] = __expf(ps1);
        tb[1 * 512 + h1 * 128 + row] = __expf(NEG_SLOPE * ps1);
        tb[2 * 512 + h1 * 128 + row] = __expf(pd1);
        tb[3 * 512 + h1 * 128 + row] = __expf(NEG_SLOPE * pd1);
      }
    }
  }

  // transpose-write hT[dim][src] (skip src 126/127 -> GEMV)
  {
    unsigned short* hT = hTws + (size_t)g * 32768;
    const int srcb = row0 + kg * 4;
#pragma unroll
    for (int nf = 0; nf < 8; ++nf) {
      int dim = dimh * 128 + nf * 16 + rl;
      unsigned lo = cvtpk(acc[nf][0], acc[nf][1]);
      unsigned hi = cvtpk(acc[nf][2], acc[nf][3]);
      if (srcb < 124) { uint2 u = { lo, hi }; *(uint2*)(hT + (size_t)dim * 128 + srcb) = u; }
      else            { *(unsigned*)(hT + (size_t)dim * 128 + srcb) = lo; }
    }
  }

  // GEMV for user/item rows (rh==1 blocks only; wave = one (row,head))
  if (rh == 1) {
    const int r2 = 126 + (tid >> 8);
    const int c2 = tid & 255;
    const float* er = (tid < 256) ? (utab + (size_t)userid[g] * 256)
                                  : (itab + (size_t)itemid[g] * 256);
    const uint4* wr = (const uint4*)(wct + (size_t)(1 + (tid >> 8)) * 65536 + (size_t)c2 * 256);
    const float4* e4 = (const float4*)er;
    float hv = 0.f;
#pragma unroll 4
    for (int j = 0; j < 32; ++j) {
      uint4 w8 = wr[j];
      float4 e0 = e4[2 * j], e1 = e4[2 * j + 1];
      const unsigned short* wp = (const unsigned short*)&w8;
      hv += e0.x * bf2f(wp[0]) + e0.y * bf2f(wp[1]) + e0.z * bf2f(wp[2]) + e0.w * bf2f(wp[3]);
      hv += e1.x * bf2f(wp[4]) + e1.y * bf2f(wp[5]) + e1.z * bf2f(wp[6]) + e1.w * bf2f(wp[7]);
    }
    float gps = hv * asl[c2];
    float gpd = hv * adl[c2];
#pragma unroll
    for (int d2 = 32; d2 >= 1; d2 >>= 1) { gps += __shfl_xor(gps, d2); gpd += __shfl_xor(gpd, d2); }
    if (lane == 0) {
      int h2 = wid & 3;
      float* tb = tabws + (size_t)g * 2048;
      tb[0 * 512 + h2 * 128 + r2] = __expf(gps);
      tb[1 * 512 + h2 * 128 + r2] = __expf(NEG_SLOPE * gps);
      tb[2 * 512 + h2 * 128 + r2] = __expf(gpd);
      tb[3 * 512 + h2 * 128 + r2] = __expf(NEG_SLOPE * gpd);
    }
    hTws[(size_t)g * 32768 + (size_t)c2 * 128 + r2] = f2bf(hv);
  }
}

// ---------------- K3: per-(graph, head) GEMM2 + fused epilogue ----------------------------
// 1024 blocks = (g, hd); 256 threads, 4 waves; 4 blocks/CU (LDS ~35 KB).
__global__ __launch_bounds__(256, 4) void k3(
    const unsigned char* __restrict__ Mws, const unsigned short* __restrict__ hTws,
    const float* __restrict__ tabws,
    const float* __restrict__ W_out, const float* __restrict__ b_out,
    float* __restrict__ out) {
  const int g = blockIdx.x & 255;
  const int hd = blockIdx.x >> 8;
  const int tid = threadIdx.x;
  const int lane = tid & 63;
  const int wid = tid >> 6;            // 0..3
  const int rl = lane & 15;
  const int kg = lane >> 4;

  __shared__ __align__(16) unsigned char Ml[16384];
  __shared__ __align__(16) unsigned short Htl[8192];   // [64 dim][128 src], SW-swizzled
  __shared__ float Es[128], Fs[128], Ed[128], Fd[128], wol[64], lpf[128];

  // stage M (linear; SWB baked at build)
  const unsigned char* Msrc = Mws + (size_t)g * 16384;
#pragma unroll
  for (int i = 0; i < 4; ++i)
    *(uint4*)(Ml + tid * 16 + i * 4096) = *(const uint4*)(Msrc + tid * 16 + i * 4096);
  // stage hT head slice with SW swizzle
  const char* hsrc = (const char*)(hTws + (size_t)g * 32768 + (size_t)hd * 8192);
#pragma unroll
  for (int i = 0; i < 4; ++i) {
    int idx = tid + i * 256;           // 16B granule, 1024 total
    int off = idx * 16;
    int dim = idx >> 4;
    uint4 v = *(const uint4*)(hsrc + off);
    *(uint4*)((char*)Htl + (off ^ SW(dim))) = v;
  }
  // stage tables (4 x 128 floats)
  {
    const float* tsrc = tabws + (size_t)g * 2048 + hd * 128;
#pragma unroll
    for (int k = 0; k < 2; ++k) {
      int f = tid * 2 + k;             // 0..511
      int tbl = f >> 7, node = f & 127;
      float v = tsrc[tbl * 512 + node];
      float* dstp = (tbl == 0) ? Es : ((tbl == 1) ? Fs : ((tbl == 2) ? Ed : Fd));
      dstp[node] = v;
    }
  }
  if (tid < 64) wol[tid] = W_out[hd * 64 + tid];
  const float bo = b_out[0];
  __syncthreads();

  const int m2 = wid * 32;
  const float Edv0 = Ed[m2 + rl],      Fdv0 = Fd[m2 + rl];
  const float Edv1 = Ed[m2 + 16 + rl], Fdv1 = Fd[m2 + 16 + rl];
  float denp0 = 0.f, denp1 = 0.f;
  f32x4 acc2[2][4] = {};

#pragma unroll
  for (int ks = 0; ks < 4; ++ks) {
    f32x4 Es0 = *(const f32x4*)(&Es[ks * 32 + kg * 8]);
    f32x4 Es1 = *(const f32x4*)(&Es[ks * 32 + kg * 8 + 4]);
    f32x4 Fs0 = *(const f32x4*)(&Fs[ks * 32 + kg * 8]);
    f32x4 Fs1 = *(const f32x4*)(&Fs[ks * 32 + kg * 8 + 4]);
    bf16x8 b2[4];
#pragma unroll
    for (int nf = 0; nf < 4; ++nf) {
      int dim = nf * 16 + rl;
      b2[nf] = *(const bf16x8*)((const char*)Htl + ((dim * 256 + ks * 64 + kg * 16) ^ SW(dim)));
    }
#pragma unroll
    for (int mf = 0; mf < 2; ++mf) {
      int d = m2 + mf * 16 + rl;
      uint2 m8 = *(const uint2*)(Ml + ((d * 128 + ks * 32 + kg * 8) ^ SWB(d)));
      float Edv = mf ? Edv1 : Edv0, Fdv = mf ? Fdv1 : Fdv0;
      float av[8], dsum = 0.f;
#pragma unroll
      for (int j = 0; j < 8; ++j) {
        float mv = (float)(int)((j < 4 ? (m8.x >> (8 * j)) : (m8.y >> (8 * (j - 4)))) & 255u);
        float w = fmaxf(((j < 4) ? Es0[j] : Es1[j - 4]) * Edv,
                        ((j < 4) ? Fs0[j] : Fs1[j - 4]) * Fdv) * mv;
        av[j] = w; dsum += w;
      }
      if (mf) denp1 += dsum; else denp0 += dsum;
      bfpack a2;
      a2.u[0] = cvtpk(av[0], av[1]); a2.u[1] = cvtpk(av[2], av[3]);
      a2.u[2] = cvtpk(av[4], av[5]); a2.u[3] = cvtpk(av[6], av[7]);
#pragma unroll
      for (int nf = 0; nf < 4; ++nf)
        acc2[mf][nf] = __builtin_amdgcn_mfma_f32_16x16x32_bf16(a2.v, b2[nf], acc2[mf][nf], 0, 0, 0);
    }
  }
  denp0 += __shfl_xor(denp0, 16); denp0 += __shfl_xor(denp0, 32);
  denp1 += __shfl_xor(denp1, 16); denp1 += __shfl_xor(denp1, 32);

  float lp[2][4] = {};
#pragma unroll
  for (int mf = 0; mf < 2; ++mf) {
#pragma unroll
    for (int i = 0; i < 4; ++i) {
      float dni = __shfl(mf ? denp1 : denp0, kg * 4 + i);
      float rd = __builtin_amdgcn_rcpf(dni + 1e-16f);
#pragma unroll
      for (int nf = 0; nf < 4; ++nf) {
        float v = acc2[mf][nf][i] * rd;
        v = (v > 0.f) ? v : (__expf(v) - 1.f);
        lp[mf][i] += v * wol[nf * 16 + rl];
      }
    }
  }
#pragma unroll
  for (int mf = 0; mf < 2; ++mf) {
#pragma unroll
    for (int i = 0; i < 4; ++i) {
      float v = lp[mf][i];
#pragma unroll
      for (int d2 = 1; d2 < 16; d2 <<= 1) v += __shfl_xor(v, d2);
      if (rl == 0) lpf[m2 + mf * 16 + kg * 4 + i] = v;
    }
  }
  __syncthreads();
  if (tid < F_) atomicAdd(&out[(size_t)g * F_ + tid], lpf[tid] + (hd == 0 ? bo : 0.f));
}

extern "C" void kernel_launch(void* const* d_in, const int* in_sizes, int n_in,
                              void* d_out, int out_size, void* d_ws, size_t ws_size,
                              hipStream_t stream) {
  const int* fid      = (const int*)d_in[0];
  const int* userid   = (const int*)d_in[1];
  const int* itemid   = (const int*)d_in[2];
  const int* ei       = (const int*)d_in[3];
  const float* ftab   = (const float*)d_in[4];
  const float* utab   = (const float*)d_in[5];
  const float* itab   = (const float*)d_in[6];
  const float* Wf     = (const float*)d_in[7];
  const float* Wu     = (const float*)d_in[8];
  const float* Wi     = (const float*)d_in[9];
  const float* Wg     = (const float*)d_in[10];
  const float* a_src  = (const float*)d_in[11];
  const float* a_dst  = (const float*)d_in[12];
  const float* W_out  = (const float*)d_in[13];
  const float* b_out  = (const float*)d_in[14];
  float* out = (float*)d_out;

  unsigned short* ws_wct = (unsigned short*)d_ws;
  unsigned char*  ws_M   = (unsigned char*)d_ws + WS_M;
  float*          ws_tab = (float*)((char*)d_ws + WS_TAB);
  unsigned short* ws_hT  = (unsigned short*)((char*)d_ws + WS_HT);

  hipLaunchKernelGGL(k0p, dim3(352), dim3(256), 0, stream,
                     Wf, Wu, Wi, Wg, ei, ws_wct, ws_M, out);
  hipLaunchKernelGGL(k1, dim3(512), dim3(512), 0, stream,
                     fid, userid, itemid, ftab, utab, itab, ws_wct,
                     a_src, a_dst, ws_tab, ws_hT);
  hipLaunchKernelGGL(k3, dim3(1024), dim3(256), 0, stream,
                     ws_M, ws_hT, ws_tab, W_out, b_out, out);
}

// Round 13
// 83.872 us; speedup vs baseline: 1.0445x; 1.0445x over previous
//
#include <hip/hip_runtime.h>
#include <math.h>

// Problem constants
#define F_ 126
#define NPG 128              // nodes per graph
#define EPG 2048             // edges per graph
#define ET 524288            // total edges
#define NEG_SLOPE 0.2f

typedef short bf16x8 __attribute__((ext_vector_type(8)));
typedef float f32x4 __attribute__((ext_vector_type(4)));

__device__ __forceinline__ float bf2f(unsigned short u) {
  return __uint_as_float(((unsigned)u) << 16);
}
__device__ __forceinline__ unsigned short f2bf(float f) {
  unsigned x = __float_as_uint(f);
  unsigned r = x + 0x7fffu + ((x >> 16) & 1u);   // RNE
  return (unsigned short)(r >> 16);
}
// single-instruction packed f32x2 -> bf16x2 (RNE), gfx950
__device__ __forceinline__ unsigned cvtpk(float lo, float hi) {
  unsigned r;
  asm("v_cvt_pk_bf16_f32 %0, %1, %2" : "=v"(r) : "v"(lo), "v"(hi));
  return r;
}
union bfpack { unsigned u[4]; bf16x8 v; };

#define SW(r)  (((r) & 7) << 4)    // bf16-row swizzle (16B granule)
#define SWB(d) (((d) & 15) << 3)   // byte-matrix swizzle (8B granule)

// ws layout: [0,384K) wct bf16 [3][256][256];  [WS_M, +4MB) M u8 [256 g][16384] (SWB)
#define WS_M    393216

// ---------------- K0P: wct (coalesced) + M multiplicity build -----------------------------
__global__ __launch_bounds__(256) void k0p(
    const float* __restrict__ Wf, const float* __restrict__ Wu,
    const float* __restrict__ Wi, const float* __restrict__ Wg,
    const int* __restrict__ ei,
    unsigned short* __restrict__ wct, unsigned char* __restrict__ Mws) {
  const int blk = blockIdx.x;
  const int tid = threadIdx.x;
  if (blk < 96) {
    const int type = blk / 32;
    const int kc = blk % 32;
    const float* Wx = (type == 0) ? Wf : ((type == 1) ? Wu : Wi);
    __shared__ float Xs[8][256];
#pragma unroll
    for (int r = 0; r < 8; ++r) Xs[r][tid] = Wx[(kc * 8 + r) * 256 + tid];  // coalesced
    __syncthreads();
    float acc[8] = {};
#pragma unroll 16
    for (int j = 0; j < 256; ++j) {
      float wg = Wg[j * 256 + tid];                // coalesced across threads
#pragma unroll
      for (int r = 0; r < 8; ++r) acc[r] += Xs[r][j] * wg;
    }
#pragma unroll
    for (int r = 0; r < 8; ++r)
      wct[((size_t)type * 256 + tid) * 256 + kc * 8 + r] = f2bf(acc[r]);
  } else {
    // per-graph M build (byte-packed multiplicity, SWB-swizzled)
    const int g = blk - 96;
    __shared__ __align__(16) unsigned char Ml[16384];
    {
      uint4 z = { 0, 0, 0, 0 };
#pragma unroll
      for (int i = 0; i < 4; ++i) *(uint4*)(Ml + tid * 16 + i * 4096) = z;
    }
    int4 sa = *(const int4*)(ei + (size_t)g * EPG + tid * 8);
    int4 sb = *(const int4*)(ei + (size_t)g * EPG + tid * 8 + 4);
    int4 da = *(const int4*)(ei + (size_t)ET + (size_t)g * EPG + tid * 8);
    int4 db = *(const int4*)(ei + (size_t)ET + (size_t)g * EPG + tid * 8 + 4);
    __syncthreads();
    int ss[8] = { sa.x - g * NPG, sa.y - g * NPG, sa.z - g * NPG, sa.w - g * NPG,
                  sb.x - g * NPG, sb.y - g * NPG, sb.z - g * NPG, sb.w - g * NPG };
    int dd[8] = { da.x - g * NPG, da.y - g * NPG, da.z - g * NPG, da.w - g * NPG,
                  db.x - g * NPG, db.y - g * NPG, db.z - g * NPG, db.w - g * NPG };
#pragma unroll
    for (int j = 0; j < 8; ++j) {
      int bofs = (dd[j] * 128 + ss[j]) ^ SWB(dd[j]);
      atomicAdd((int*)(Ml + (bofs & ~3)), 1 << ((bofs & 3) * 8));
    }
    __syncthreads();
    unsigned char* Mdst = Mws + (size_t)g * 16384;
#pragma unroll
    for (int i = 0; i < 4; ++i)
      *(uint4*)(Mdst + tid * 16 + i * 4096) = *(const uint4*)(Ml + tid * 16 + i * 4096);
  }
}

// ---------------- K2F: fused per-graph kernel (1024 thr, 1 block/graph) -------------------
#define OFF_HT   0
#define OFF_M    65536
#define OFF_ES   81920
#define OFF_FS   83968
#define OFF_ED   86016
#define OFF_FD   88064
#define OFF_ASL  90112
#define OFF_ADL  91136
#define OFF_WO   92160
#define OFF_LP   93184
#define LDS_SZ   94208

__global__ __launch_bounds__(1024, 1) void k2f(
    const int* __restrict__ fid, const int* __restrict__ userid, const int* __restrict__ itemid,
    const float* __restrict__ ftab, const float* __restrict__ utab, const float* __restrict__ itab,
    const unsigned short* __restrict__ wct, const unsigned char* __restrict__ Mws,
    const float* __restrict__ a_src, const float* __restrict__ a_dst,
    const float* __restrict__ W_out, const float* __restrict__ b_out,
    float* __restrict__ out) {
  __shared__ __align__(16) char smem[LDS_SZ];
  const int g = blockIdx.x;
  const int tid = threadIdx.x;
  const int lane = tid & 63;
  const int wid = tid >> 6;          // 0..15
  const int rl = lane & 15;
  const int kg = lane >> 4;

  char* Ht = smem + OFF_HT;
  char* Mb = smem + OFF_M;
  float* EsT = (float*)(smem + OFF_ES);   // [hd*128 + node]
  float* FsT = (float*)(smem + OFF_FS);
  float* EdT = (float*)(smem + OFF_ED);
  float* FdT = (float*)(smem + OFF_FD);
  float* asl = (float*)(smem + OFF_ASL);
  float* adl = (float*)(smem + OFF_ADL);
  float* wo  = (float*)(smem + OFF_WO);
  float* lpf = (float*)(smem + OFF_LP);

  // T14: M staging load now, LDS write before b1
  uint4 mstage = *(const uint4*)(Mws + (size_t)g * 16384 + tid * 16);

  if (tid < 256)      { asl[tid] = a_src[tid]; wo[tid] = W_out[tid]; }
  else if (tid < 512) { adl[tid - 256] = a_dst[tid - 256]; }
  const float bo = b_out[0];
  __syncthreads();                                           // b0

  // ---- GEMM1: h = emb @ Wc(type0); wave = 16 rows (rowg) x 128 dims (dimh) ----
  const int rowg = wid & 7, dimh = wid >> 3;
  const int arow = rowg * 16 + rl;
  const float* rp;
  if (arow < F_)       rp = ftab + (size_t)fid[g * F_ + arow] * 256;
  else if (arow == F_) rp = utab + (size_t)userid[g] * 256;  // placeholder; GEMV fixes 126/127
  else                 rp = itab + (size_t)itemid[g] * 256;
  const unsigned short* bp[8];
#pragma unroll
  for (int nf = 0; nf < 8; ++nf)
    bp[nf] = wct + (size_t)(dimh * 128 + nf * 16 + rl) * 256;

  f32x4 acc[8] = {};
  // 2-deep A pipeline with NAMED buffers only (no loop-indexed arrays)
  float4 A0a = *(const float4*)(rp + kg * 8);
  float4 A0b = *(const float4*)(rp + kg * 8 + 4);
  float4 A1a, A1b;

#pragma unroll
  for (int kk = 0; kk < 4; ++kk) {
    const int koA = (2 * kk + 1) * 32 + kg * 8;
    A1a = *(const float4*)(rp + koA);
    A1b = *(const float4*)(rp + koA + 4);
    {
      const int koB = (2 * kk) * 32 + kg * 8;
      bf16x8 Bv[8];
#pragma unroll
      for (int nf = 0; nf < 8; ++nf) Bv[nf] = *(const bf16x8*)(bp[nf] + koB);
      bfpack p;
      p.u[0] = cvtpk(A0a.x, A0a.y); p.u[1] = cvtpk(A0a.z, A0a.w);
      p.u[2] = cvtpk(A0b.x, A0b.y); p.u[3] = cvtpk(A0b.z, A0b.w);
#pragma unroll
      for (int nf = 0; nf < 8; ++nf)
        acc[nf] = __builtin_amdgcn_mfma_f32_16x16x32_bf16(p.v, Bv[nf], acc[nf], 0, 0, 0);
    }
    if (kk < 3) {
      const int koC = (2 * kk + 2) * 32 + kg * 8;
      A0a = *(const float4*)(rp + koC);
      A0b = *(const float4*)(rp + koC + 4);
    }
    {
      bf16x8 Bv[8];
#pragma unroll
      for (int nf = 0; nf < 8; ++nf) Bv[nf] = *(const bf16x8*)(bp[nf] + koA);
      bfpack p;
      p.u[0] = cvtpk(A1a.x, A1a.y); p.u[1] = cvtpk(A1a.z, A1a.w);
      p.u[2] = cvtpk(A1b.x, A1b.y); p.u[3] = cvtpk(A1b.z, A1b.w);
#pragma unroll
      for (int nf = 0; nf < 8; ++nf)
        acc[nf] = __builtin_amdgcn_mfma_f32_16x16x32_bf16(p.v, Bv[nf], acc[nf], 0, 0, 0);
    }
  }

  // ---- exp tables from f32 acc (heads dimh*2, dimh*2+1) ----
  {
    float asv[8], adv[8];
#pragma unroll
    for (int nf = 0; nf < 8; ++nf) {
      asv[nf] = asl[dimh * 128 + nf * 16 + rl];
      adv[nf] = adl[dimh * 128 + nf * 16 + rl];
    }
#pragma unroll
    for (int i = 0; i < 4; ++i) {
      float ps0 = 0.f, ps1 = 0.f, pd0 = 0.f, pd1 = 0.f;
#pragma unroll
      for (int nf = 0; nf < 4; ++nf) {
        ps0 += acc[nf][i] * asv[nf];         pd0 += acc[nf][i] * adv[nf];
        ps1 += acc[nf + 4][i] * asv[nf + 4]; pd1 += acc[nf + 4][i] * adv[nf + 4];
      }
#pragma unroll
      for (int d2 = 1; d2 < 16; d2 <<= 1) {
        ps0 += __shfl_xor(ps0, d2); ps1 += __shfl_xor(ps1, d2);
        pd0 += __shfl_xor(pd0, d2); pd1 += __shfl_xor(pd1, d2);
      }
      int row = rowg * 16 + kg * 4 + i;
      if (rl == 0 && row < F_) {
        int h0 = dimh * 2, h1 = h0 + 1;
        EsT[h0 * 128 + row] = __expf(ps0);
        FsT[h0 * 128 + row] = __expf(NEG_SLOPE * ps0);
        EdT[h0 * 128 + row] = __expf(pd0);
        FdT[h0 * 128 + row] = __expf(NEG_SLOPE * pd0);
        EsT[h1 * 128 + row] = __expf(ps1);
        FsT[h1 * 128 + row] = __expf(NEG_SLOPE * ps1);
        EdT[h1 * 128 + row] = __expf(pd1);
        FdT[h1 * 128 + row] = __expf(NEG_SLOPE * pd1);
      }
    }
  }

  // ---- transpose-write hT[dim][src] (src 126/127 via GEMV) ----
  {
    const int srcb = rowg * 16 + kg * 4;
#pragma unroll
    for (int nf = 0; nf < 8; ++nf) {
      int dim = dimh * 128 + nf * 16 + rl;
      unsigned lo = cvtpk(acc[nf][0], acc[nf][1]);
      unsigned hi = cvtpk(acc[nf][2], acc[nf][3]);
      int bofs = (dim * 256 + srcb * 2) ^ SW(dim);
      if (srcb < 124) { uint2 u = { lo, hi }; *(uint2*)(Ht + bofs) = u; }
      else            { *(unsigned*)(Ht + bofs) = lo; }
    }
  }

  // ---- GEMV: user/item source rows (threads 0..511) ----
  if (tid < 512) {
    const int r2 = F_ + (tid >> 8);
    const int c2 = tid & 255;
    const float* er = (tid < 256) ? (utab + (size_t)userid[g] * 256)
                                  : (itab + (size_t)itemid[g] * 256);
    const uint4* wr = (const uint4*)(wct + (size_t)(1 + (tid >> 8)) * 65536 + (size_t)c2 * 256);
    const float4* e4 = (const float4*)er;
    float hv = 0.f;
#pragma unroll 4
    for (int j = 0; j < 32; ++j) {
      uint4 w8 = wr[j];
      float4 e0 = e4[2 * j], e1 = e4[2 * j + 1];
      const unsigned short* wp = (const unsigned short*)&w8;
      hv += e0.x * bf2f(wp[0]) + e0.y * bf2f(wp[1]) + e0.z * bf2f(wp[2]) + e0.w * bf2f(wp[3]);
      hv += e1.x * bf2f(wp[4]) + e1.y * bf2f(wp[5]) + e1.z * bf2f(wp[6]) + e1.w * bf2f(wp[7]);
    }
    float gps = hv * asl[c2];
    float gpd = hv * adl[c2];
#pragma unroll
    for (int d2 = 32; d2 >= 1; d2 >>= 1) { gps += __shfl_xor(gps, d2); gpd += __shfl_xor(gpd, d2); }
    if (lane == 0) {
      int h2 = wid & 3;
      EsT[h2 * 128 + r2] = __expf(gps);
      FsT[h2 * 128 + r2] = __expf(NEG_SLOPE * gps);
      EdT[h2 * 128 + r2] = __expf(gpd);
      FdT[h2 * 128 + r2] = __expf(NEG_SLOPE * gpd);
    }
    *(unsigned short*)(Ht + ((c2 * 256 + r2 * 2) ^ SW(c2))) = f2bf(hv);
  }

  // T14 write-late: M into LDS
  *(uint4*)(Mb + tid * 16) = mstage;
  __syncthreads();                                           // b1: M, hT, exp tables ready

  // ---- 4 head passes, barrier-free; A[d][s] = M[d][s] * max(Es[s]Ed[d], Fs[s]Fd[d]) ----
  float lp[4] = {};
  const int m2 = (wid & 7) * 16, n2 = (wid >> 3) * 32;
  const int drow = m2 + rl;

  for (int hd = 0; hd < 4; ++hd) {
    const float Edv = EdT[hd * 128 + drow];
    const float Fdv = FdT[hd * 128 + drow];
    float denp = 0.f;
    f32x4 acc2[2] = {};
#pragma unroll
    for (int ks = 0; ks < 4; ++ks) {
      uint2 m8 = *(const uint2*)(Mb + ((drow * 128 + ks * 32 + kg * 8) ^ SWB(drow)));
      f32x4 Es0 = *(const f32x4*)(&EsT[hd * 128 + ks * 32 + kg * 8]);
      f32x4 Es1 = *(const f32x4*)(&EsT[hd * 128 + ks * 32 + kg * 8 + 4]);
      f32x4 Fs0 = *(const f32x4*)(&FsT[hd * 128 + ks * 32 + kg * 8]);
      f32x4 Fs1 = *(const f32x4*)(&FsT[hd * 128 + ks * 32 + kg * 8 + 4]);
      float av[8];
#pragma unroll
      for (int j = 0; j < 8; ++j) {
        float mv = (float)(int)((j < 4 ? (m8.x >> (8 * j)) : (m8.y >> (8 * (j - 4)))) & 255u);
        float w = fmaxf(((j < 4) ? Es0[j] : Es1[j - 4]) * Edv,
                        ((j < 4) ? Fs0[j] : Fs1[j - 4]) * Fdv) * mv;
        av[j] = w;
        denp += w;
      }
      bfpack a2;
      a2.u[0] = cvtpk(av[0], av[1]); a2.u[1] = cvtpk(av[2], av[3]);
      a2.u[2] = cvtpk(av[4], av[5]); a2.u[3] = cvtpk(av[6], av[7]);
      bf16x8 b2[2];
#pragma unroll
      for (int nf = 0; nf < 2; ++nf) {
        int dim = hd * 64 + n2 + nf * 16 + rl;
        b2[nf] = *(const bf16x8*)(Ht + ((dim * 256 + ks * 64 + kg * 16) ^ SW(dim)));
      }
#pragma unroll
      for (int nf = 0; nf < 2; ++nf)
        acc2[nf] = __builtin_amdgcn_mfma_f32_16x16x32_bf16(a2.v, b2[nf], acc2[nf], 0, 0, 0);
    }
    denp += __shfl_xor(denp, 16);
    denp += __shfl_xor(denp, 32);
#pragma unroll
    for (int i = 0; i < 4; ++i) {
      float dni = __shfl(denp, kg * 4 + i);
      float rd = __builtin_amdgcn_rcpf(dni + 1e-16f);
#pragma unroll
      for (int nf = 0; nf < 2; ++nf) {
        float v = acc2[nf][i] * rd;
        v = (v > 0.f) ? v : (__expf(v) - 1.f);
        lp[i] += v * wo[hd * 64 + n2 + nf * 16 + rl];
      }
    }
  }

  // ---- readout reduce + direct store ----
#pragma unroll
  for (int i = 0; i < 4; ++i) {
    float v = lp[i];
#pragma unroll
    for (int d2 = 1; d2 < 16; d2 <<= 1) v += __shfl_xor(v, d2);
    if (rl == 0) lpf[(m2 + kg * 4 + i) * 2 + (wid >> 3)] = v;
  }
  __syncthreads();                                           // b2
  if (tid < F_) out[(size_t)g * F_ + tid] = lpf[tid * 2] + lpf[tid * 2 + 1] + bo;
}

extern "C" void kernel_launch(void* const* d_in, const int* in_sizes, int n_in,
                              void* d_out, int out_size, void* d_ws, size_t ws_size,
                              hipStream_t stream) {
  const int* fid      = (const int*)d_in[0];
  const int* userid   = (const int*)d_in[1];
  const int* itemid   = (const int*)d_in[2];
  const int* ei       = (const int*)d_in[3];
  const float* ftab   = (const float*)d_in[4];
  const float* utab   = (const float*)d_in[5];
  const float* itab   = (const float*)d_in[6];
  const float* Wf     = (const float*)d_in[7];
  const float* Wu     = (const float*)d_in[8];
  const float* Wi     = (const float*)d_in[9];
  const float* Wg     = (const float*)d_in[10];
  const float* a_src  = (const float*)d_in[11];
  const float* a_dst  = (const float*)d_in[12];
  const float* W_out  = (const float*)d_in[13];
  const float* b_out  = (const float*)d_in[14];
  float* out = (float*)d_out;

  unsigned short* ws_wct = (unsigned short*)d_ws;
  unsigned char*  ws_M   = (unsigned char*)d_ws + WS_M;

  hipLaunchKernelGGL(k0p, dim3(352), dim3(256), 0, stream, Wf, Wu, Wi, Wg, ei, ws_wct, ws_M);
  hipLaunchKernelGGL(k2f, dim3(256), dim3(1024), 0, stream,
                     fid, userid, itemid, ftab, utab, itab, ws_wct, ws_M,
                     a_src, a_dst, W_out, b_out, out);
}